// Round 6
// baseline (194.178 us; speedup 1.0000x reference)
//
#include <hip/hip_runtime.h>
#include <math.h>

typedef __attribute__((ext_vector_type(8))) short bf16x8;
typedef __attribute__((ext_vector_type(4))) float f32x4;

// packed f32x2 -> bf16x2 (RTNE). No builtin on gfx950 -> inline asm.
static __device__ __forceinline__ unsigned int cvtpk(float lo, float hi) {
  unsigned int r;
  asm("v_cvt_pk_bf16_f32 %0, %1, %2" : "=v"(r) : "v"(lo), "v"(hi));
  return r;
}

// ---------------- prep kernel ----------------
// LDS-tiled transposes (coalesced reads AND writes — the old version did 262k
// scattered 2-B stores, ~60 us/iter). Grid: 66 blocks x 256 threads.
//   bid 0..31 : W1 [256][512] -> W1T bf16 [512][256], 64x64 tiles (4x8)
//   bid 32..63: W2 [512][256] -> W2T bf16 [256][512], 64x64 tiles (8x4)
//   bid 64    : memB: memory [50][256] -> bf16 [64][256] zero-padded
//   bid 65    : msq[64]
__global__ void prep_weights(const float* __restrict__ W1,
                             const float* __restrict__ W2,
                             const float* __restrict__ mem,
                             unsigned short* __restrict__ W1T,
                             unsigned short* __restrict__ W2T,
                             unsigned short* __restrict__ memB,
                             float* __restrict__ msq) {
  const int bid = blockIdx.x, tid = threadIdx.x;
  if (bid < 64) {
    __shared__ float tile[64][65];
    const float* src;
    unsigned short* dst;
    int C, Cd, k0, n0;
    if (bid < 32) {
      src = W1; dst = W1T; C = 512; Cd = 256;
      k0 = (bid >> 3) * 64; n0 = (bid & 7) * 64;
    } else {
      int t = bid - 32;
      src = W2; dst = W2T; C = 256; Cd = 512;
      k0 = (t >> 2) * 64; n0 = (t & 3) * 64;
    }
    // load 64x64 f32 tile, coalesced
    int r = tid >> 2, c4 = (tid & 3) * 16;
    const float4* s4 = (const float4*)(src + (k0 + r) * C + n0 + c4);
#pragma unroll
    for (int j = 0; j < 4; ++j) {
      float4 v = s4[j];
      tile[r][c4 + j * 4 + 0] = v.x;
      tile[r][c4 + j * 4 + 1] = v.y;
      tile[r][c4 + j * 4 + 2] = v.z;
      tile[r][c4 + j * 4 + 3] = v.w;
    }
    __syncthreads();
    // store transposed as bf16, coalesced (32 B per thread)
    int nl = tid >> 2, kq = (tid & 3) * 16;
    unsigned int o[8];
#pragma unroll
    for (int j = 0; j < 8; ++j)
      o[j] = cvtpk(tile[kq + 2 * j][nl], tile[kq + 2 * j + 1][nl]);
    unsigned short* dp = dst + (n0 + nl) * Cd + k0 + kq;
    *(uint4*)(dp) = make_uint4(o[0], o[1], o[2], o[3]);
    *(uint4*)(dp + 8) = make_uint4(o[4], o[5], o[6], o[7]);
  } else if (bid == 64) {
    // memB: 16384 bf16, 64 elems/thread, vectorized
    int j0 = tid * 64;
#pragma unroll
    for (int j = 0; j < 16; ++j) {
      int e = j0 + j * 4;
      int rrow = e >> 8;
      uint2 w;
      if (rrow < 50) {
        float4 v = *(const float4*)(mem + e);
        w = make_uint2(cvtpk(v.x, v.y), cvtpk(v.z, v.w));
      } else {
        w = make_uint2(0u, 0u);
      }
      *(uint2*)(memB + e) = w;
    }
  } else {
    // msq: 4 threads per memory row
    int rrow = tid >> 2, c0 = (tid & 3) * 64;
    float s = 0.f;
    if (rrow < 50) {
      const float4* m4 = (const float4*)(mem + rrow * 256 + c0);
#pragma unroll
      for (int c = 0; c < 16; ++c) {
        float4 v = m4[c];
        s += v.x * v.x + v.y * v.y + v.z * v.z + v.w * v.w;
      }
    }
    s += __shfl_xor(s, 1, 64);
    s += __shfl_xor(s, 2, 64);
    if ((tid & 3) == 0) msq[rrow] = (rrow < 50) ? s : 1e30f;
  }
}

// ---------------- fused main kernel ----------------
// 64 tokens/block, 1024 blocks, 512 threads (8 waves). Same 65536-B LDS and
// tile as R5, but work split 8 ways: per-wave regs halve (acc2 32, acc1 16)
// -> compiler can pipeline L2 weight loads; 4 waves/SIMD hide latency.
//   Xs : [0, 32768)      swizzled dense [64][256] bf16 (row 512 B); later feats
//   Hs0: [32768, 49152)  swizzled dense [64][128] bf16 (row 256 B)  } double
//   Hs1: [49152, 65536)                                             } buffer
// Aliases: red (1728 f32) aliases Hs0; distS [64][53] aliases Xs.
// Phase-1 pipeline (one barrier per chunk):
//   [GEMM2(cc-1) ; GEMM1(cc)->Hs(cc&1) ; bar] cc=0..3, then GEMM2(3).
#define DPitch 53
#define SWZ(b, r) ((b) ^ (((r) & 7) << 4))

__global__ __launch_bounds__(512, 4) void fused_main(
    const float* __restrict__ X, const float* __restrict__ b1v,
    const float* __restrict__ b2v, const float* __restrict__ gammav,
    const float* __restrict__ betav, const unsigned short* __restrict__ W1T,
    const unsigned short* __restrict__ W2T,
    const unsigned short* __restrict__ memB, const float* __restrict__ msq,
    float* __restrict__ out) {
  __shared__ __align__(16) char smem[65536];
  float* distS = (float*)smem;             // aliases Xs
  float* red = (float*)(smem + 32768);     // aliases Hs0
  float* psum   = red;         // [8][64]
  float* psumsq = red + 512;   // [8][64]
  float* fsqp   = red + 1024;  // [8][64]
  float* muS    = red + 1536;  // [64]
  float* rstdS  = red + 1600;  // [64]
  float* fsqS   = red + 1664;  // [64]  (1728 f32 = 6912 B < 16384)

  const char* W1Tc = (const char*)W1T;  // row stride 512 B
  const char* W2Tc = (const char*)W2T;  // row stride 1024 B

  const int tid = threadIdx.x;
  const int wid = tid >> 6;  // 0..7
  const int lane = tid & 63;
  const int l16 = lane & 15;
  const int quad = lane >> 4;

  // ---- Phase 0: stage X tile [64][256] fp32 -> swizzled LDS bf16 ----
  const float4* X4 = (const float4*)(X + (size_t)blockIdx.x * 64 * 256);
#pragma unroll
  for (int j = 0; j < 8; ++j) {
    int row = j * 8 + wid;
    float4 v = X4[row * 64 + lane];
    *(uint2*)(smem + SWZ(row * 512 + lane * 8, row)) =
        make_uint2(cvtpk(v.x, v.y), cvtpk(v.z, v.w));
  }

  // F^T accumulators: fcol = wid*32 + mt*16 + quad*4 + reg, token = nt*16+l16
  f32x4 acc2[2][4];
#pragma unroll
  for (int mt = 0; mt < 2; ++mt) {
    const float4 bb = *(const float4*)(&b2v[wid * 32 + mt * 16 + quad * 4]);
#pragma unroll
    for (int nt = 0; nt < 4; ++nt) {
      acc2[mt][nt][0] = bb.x; acc2[mt][nt][1] = bb.y;
      acc2[mt][nt][2] = bb.z; acc2[mt][nt][3] = bb.w;
    }
  }

  __syncthreads();

  // ---- Phase 1: software-pipelined chunks (128 hcols each) ----
#pragma unroll
  for (int cc = 0; cc < 4; ++cc) {
    // -- GEMM2(cc-1): F^T += W2T[:, (cc-1)*128:+128] x Hs[(cc-1)&1] --
    if (cc > 0) {
      const char* HsR = smem + 32768 + ((cc - 1) & 1) * 16384;
#pragma unroll
      for (int k2 = 0; k2 < 4; ++k2) {
        bf16x8 a[2], b[4];
#pragma unroll
        for (int mt = 0; mt < 2; ++mt)
          a[mt] = *(const bf16x8*)(W2Tc + (wid * 32 + mt * 16 + l16) * 1024 +
                                   (cc - 1) * 256 + k2 * 64 + quad * 16);
#pragma unroll
        for (int nt = 0; nt < 4; ++nt) {
          int r = nt * 16 + l16;
          b[nt] = *(const bf16x8*)(HsR + SWZ(r * 256 + k2 * 64 + quad * 16, r));
        }
#pragma unroll
        for (int mt = 0; mt < 2; ++mt)
#pragma unroll
          for (int nt = 0; nt < 4; ++nt)
            acc2[mt][nt] = __builtin_amdgcn_mfma_f32_16x16x32_bf16(
                a[mt], b[nt], acc2[mt][nt], 0, 0, 0);
      }
    }

    // -- GEMM1(cc): 16 hcols/wave x 64 tokens, K=256 --
    int hbase = cc * 128 + wid * 16;
    f32x4 acc1[4];
    {
      const float4 bb = *(const float4*)(&b1v[hbase + quad * 4]);
#pragma unroll
      for (int nt = 0; nt < 4; ++nt) {
        acc1[nt][0] = bb.x; acc1[nt][1] = bb.y;
        acc1[nt][2] = bb.z; acc1[nt][3] = bb.w;
      }
    }
#pragma unroll
    for (int kk = 0; kk < 8; ++kk) {
      int kb = kk * 64 + quad * 16;
      bf16x8 a = *(const bf16x8*)(W1Tc + (hbase + l16) * 512 + kb);
      bf16x8 b[4];
#pragma unroll
      for (int nt = 0; nt < 4; ++nt) {
        int r = nt * 16 + l16;
        b[nt] = *(const bf16x8*)(smem + SWZ(r * 512 + kb, r));
      }
#pragma unroll
      for (int nt = 0; nt < 4; ++nt)
        acc1[nt] = __builtin_amdgcn_mfma_f32_16x16x32_bf16(a, b[nt], acc1[nt], 0, 0, 0);
    }
    // -- epilogue(cc): relu -> bf16 -> Hs[cc&1][token][wid*16+quad*4 ..+4] --
    {
      char* HsW = smem + 32768 + (cc & 1) * 16384;
#pragma unroll
      for (int nt = 0; nt < 4; ++nt) {
        int token = nt * 16 + l16;
        f32x4 v = acc1[nt];
        *(uint2*)(HsW + SWZ(token * 256 + wid * 32 + quad * 8, token)) =
            make_uint2(cvtpk(fmaxf(v[0], 0.f), fmaxf(v[1], 0.f)),
                       cvtpk(fmaxf(v[2], 0.f), fmaxf(v[3], 0.f)));
      }
    }
    __syncthreads();
  }

  // -- GEMM2(3): tail (reads Hs1; red aliases Hs0 only) --
  {
    const char* HsR = smem + 32768 + 16384;
#pragma unroll
    for (int k2 = 0; k2 < 4; ++k2) {
      bf16x8 a[2], b[4];
#pragma unroll
      for (int mt = 0; mt < 2; ++mt)
        a[mt] = *(const bf16x8*)(W2Tc + (wid * 32 + mt * 16 + l16) * 1024 +
                                 3 * 256 + k2 * 64 + quad * 16);
#pragma unroll
      for (int nt = 0; nt < 4; ++nt) {
        int r = nt * 16 + l16;
        b[nt] = *(const bf16x8*)(HsR + SWZ(r * 256 + k2 * 64 + quad * 16, r));
      }
#pragma unroll
      for (int mt = 0; mt < 2; ++mt)
#pragma unroll
        for (int nt = 0; nt < 4; ++nt)
          acc2[mt][nt] = __builtin_amdgcn_mfma_f32_16x16x32_bf16(
              a[mt], b[nt], acc2[mt][nt], 0, 0, 0);
    }
  }

  // ---- Phase 2a: per-token sum/sumsq for LayerNorm ----
#pragma unroll
  for (int nt = 0; nt < 4; ++nt) {
    float s = 0.f, sq = 0.f;
#pragma unroll
    for (int mt = 0; mt < 2; ++mt)
#pragma unroll
      for (int r = 0; r < 4; ++r) {
        float v = acc2[mt][nt][r];
        s += v; sq += v * v;
      }
    s += __shfl_xor(s, 16, 64); sq += __shfl_xor(sq, 16, 64);
    s += __shfl_xor(s, 32, 64); sq += __shfl_xor(sq, 32, 64);
    if (quad == 0) {
      psum[wid * 64 + nt * 16 + l16] = s;
      psumsq[wid * 64 + nt * 16 + l16] = sq;
    }
  }
  __syncthreads();
  if (tid < 64) {
    float s = 0.f, sq = 0.f;
#pragma unroll
    for (int w = 0; w < 8; ++w) {
      s += psum[w * 64 + tid];
      sq += psumsq[w * 64 + tid];
    }
    float mu = s * (1.f / 256.f);
    float var = sq * (1.f / 256.f) - mu * mu;
    muS[tid] = mu;
    rstdS[tid] = rsqrtf(var + 1e-5f);
  }
  __syncthreads();

  // ---- Phase 2b: normalize in-register, write feats bf16 over Xs, fsq ----
  {
    float4 g[2], be_[2];
#pragma unroll
    for (int mt = 0; mt < 2; ++mt) {
      g[mt]   = *(const float4*)(&gammav[wid * 32 + mt * 16 + quad * 4]);
      be_[mt] = *(const float4*)(&betav[wid * 32 + mt * 16 + quad * 4]);
    }
#pragma unroll
    for (int nt = 0; nt < 4; ++nt) {
      int token = nt * 16 + l16;
      float mu = muS[token], rs = rstdS[token];
      float fs = 0.f;
#pragma unroll
      for (int mt = 0; mt < 2; ++mt) {
        float y0 = (acc2[mt][nt][0] - mu) * rs * g[mt].x + be_[mt].x;
        float y1 = (acc2[mt][nt][1] - mu) * rs * g[mt].y + be_[mt].y;
        float y2 = (acc2[mt][nt][2] - mu) * rs * g[mt].z + be_[mt].z;
        float y3 = (acc2[mt][nt][3] - mu) * rs * g[mt].w + be_[mt].w;
        fs += y0 * y0 + y1 * y1 + y2 * y2 + y3 * y3;
        *(uint2*)(smem + SWZ(token * 512 + wid * 64 + mt * 32 + quad * 8, token)) =
            make_uint2(cvtpk(y0, y1), cvtpk(y2, y3));
      }
      fs += __shfl_xor(fs, 16, 64);
      fs += __shfl_xor(fs, 32, 64);
      if (quad == 0) fsqp[wid * 64 + token] = fs;
    }
  }
  __syncthreads();
  if (tid < 64) {
    float fs = 0.f;
#pragma unroll
    for (int w = 0; w < 8; ++w) fs += fsqp[w * 64 + tid];
    fsqS[tid] = fs;
  }
  __syncthreads();

  // ---- Phase 3: dots GEMM, 8-way split: wave = (token quarter, mem half) ----
  {
    const int th = wid & 3, mh = wid >> 2;
    f32x4 acc3[2];
#pragma unroll
    for (int j = 0; j < 2; ++j) {
      acc3[j][0] = 0.f; acc3[j][1] = 0.f; acc3[j][2] = 0.f; acc3[j][3] = 0.f;
    }
    const int ar = th * 16 + l16;
#pragma unroll
    for (int kk = 0; kk < 8; ++kk) {
      int kb = kk * 64 + quad * 16;
      bf16x8 a = *(const bf16x8*)(smem + SWZ(ar * 512 + kb, ar));
      int k0 = kk * 32 + quad * 8;
#pragma unroll
      for (int j = 0; j < 2; ++j) {
        bf16x8 b = *(const bf16x8*)(memB + (mh * 32 + j * 16 + l16) * 256 + k0);
        acc3[j] = __builtin_amdgcn_mfma_f32_16x16x32_bf16(a, b, acc3[j], 0, 0, 0);
      }
    }
    // distS aliases Xs: all waves must finish feats reads first.
    __syncthreads();
    float4 fsq4 = *(const float4*)(&fsqS[th * 16 + quad * 4]);
#pragma unroll
    for (int j = 0; j < 2; ++j) {
      int col = mh * 32 + j * 16 + l16;
      float mq = msq[col];
#pragma unroll
      for (int r = 0; r < 4; ++r) {
        float fv = (r == 0) ? fsq4.x : (r == 1) ? fsq4.y : (r == 2) ? fsq4.z : fsq4.w;
        float d2 = fv + mq - 2.f * acc3[j][r];
        float d = sqrtf(fmaxf(d2, 0.f));
        int row = th * 16 + quad * 4 + r;
        if (col < 50) distS[row * DPitch + col] = d;
      }
    }
  }
  __syncthreads();

  // ---- Phase 4: top-5 smallest of 50, mean, sigmoid ----
  if (tid < 64) {
    float b0 = 1e30f, b1 = 1e30f, b2 = 1e30f, b3 = 1e30f, b4 = 1e30f;
    const float* dr = &distS[tid * DPitch];
    for (int j = 0; j < 50; ++j) {
      float v = dr[j];
      b4 = fminf(b4, v);
      float t;
      if (b4 < b3) { t = b3; b3 = b4; b4 = t; }
      if (b3 < b2) { t = b2; b2 = b3; b3 = t; }
      if (b2 < b1) { t = b1; b1 = b2; b2 = t; }
      if (b1 < b0) { t = b0; b0 = b1; b1 = t; }
    }
    float avg = (b0 + b1 + b2 + b3 + b4) * 0.2f;
    float sarg = avg - 1.f;
    out[blockIdx.x * 64 + tid] = 1.f / (1.f + __expf(-sarg));
  }
}

// ---------------- launch ----------------
extern "C" void kernel_launch(void* const* d_in, const int* in_sizes, int n_in,
                              void* d_out, int out_size, void* d_ws, size_t ws_size,
                              hipStream_t stream) {
  const float* X   = (const float*)d_in[0];  // [8*8192][256]
  const float* mem = (const float*)d_in[1];  // [50][256]
  const float* W1  = (const float*)d_in[2];  // [256][512]
  const float* b1  = (const float*)d_in[3];  // [512]
  const float* W2  = (const float*)d_in[4];  // [512][256]
  const float* b2  = (const float*)d_in[5];  // [256]
  const float* g   = (const float*)d_in[6];  // [256]
  const float* be  = (const float*)d_in[7];  // [256]
  float* out = (float*)d_out;                // [65536]

  unsigned short* W1T  = (unsigned short*)d_ws;   // [512][256] bf16
  unsigned short* W2T  = W1T + 131072;            // [256][512] bf16
  unsigned short* memB = W2T + 131072;            // [64][256] bf16
  float* msq = (float*)(memB + 16384);            // [64] fp32

  prep_weights<<<66, 256, 0, stream>>>(W1, W2, mem, W1T, W2T, memB, msq);
  fused_main<<<1024, 512, 0, stream>>>(X, b1, b2, g, be, W1T, W2T, memB, msq, out);
}